// Round 16
// baseline (210.750 us; speedup 1.0000x reference)
//
#include <hip/hip_runtime.h>

#define EPS 1e-5f

typedef __bf16 bf16_t;
typedef __bf16 bf16x8 __attribute__((ext_vector_type(8)));
typedef __bf16 bf16x4 __attribute__((ext_vector_type(4)));
typedef float f32x4 __attribute__((ext_vector_type(4)));

__device__ __forceinline__ float silu_f(float x) { return x / (1.f + __expf(-x)); }

// ---------------- block reduction (256 threads = 4 waves) ----------------
__device__ __forceinline__ float block_sum(float v, float* tmp) {
#pragma unroll
  for (int off = 32; off > 0; off >>= 1) v += __shfl_down(v, off);
  __syncthreads();
  if ((threadIdx.x & 63) == 0) tmp[threadIdx.x >> 6] = v;
  __syncthreads();
  return tmp[0] + tmp[1] + tmp[2] + tmp[3];
}

// ---------------- cast f32 -> bf16 (grid-stride, streaming) ----------------
__global__ __launch_bounds__(256) void cast_w(
    const float* __restrict__ X, bf16_t* __restrict__ Y, long n8) {
  for (long i = (long)blockIdx.x * 256 + threadIdx.x; i < n8; i += (long)gridDim.x * 256) {
    float4 v0 = *(const float4*)(X + i * 8);
    float4 v1 = *(const float4*)(X + i * 8 + 4);
    bf16x8 o;
    o[0] = (bf16_t)v0.x; o[1] = (bf16_t)v0.y; o[2] = (bf16_t)v0.z; o[3] = (bf16_t)v0.w;
    o[4] = (bf16_t)v1.x; o[5] = (bf16_t)v1.y; o[6] = (bf16_t)v1.z; o[7] = (bf16_t)v1.w;
    *(bf16x8*)(Y + i * 8) = o;
  }
}

// ============================================================================
// gemm_wb: Cpart[z](bf16) = A(256,K)bf16 @ B(N,K)^T bf16 -- full-M tile.
// 256x128, BK=64, 1024 threads (16 waves, wave-tile 64x32).
// B (pre-cast bf16) issued EXACTLY ONCE across the grid (BM = full M);
// A (4.2 MB unique) re-read per n-tile but L2-resident. Half the per-step
// load count vs the f32-B variant. Simple 2-sync loop (r7-proven).
// Grid: (N/128, S); KS = K/S; nt = KS/64 >= 1.
// ============================================================================
__global__ __launch_bounds__(1024) void gemm_wb(
    const bf16_t* __restrict__ A, const bf16_t* __restrict__ B,
    bf16_t* __restrict__ Cpart, int N, int K, int KS) {
  __shared__ bf16_t As[256][72];
  __shared__ bf16_t Bs[128][72];
  const int t = threadIdx.x;
  const int lane = t & 63;
  const int w = t >> 6;
  const int n0 = blockIdx.x * 128;
  const int kbeg = blockIdx.y * KS;
  const int nt = KS >> 6;
  const int ar = t >> 2, ac = (t & 3) * 16;  // A: 4 thr/row, 16 elts
  const int br = t >> 3, bc = (t & 7) * 8;   // B: 8 thr/row, 8 elts
  const bf16_t* Ap = A + (size_t)ar * K + kbeg + ac;
  const bf16_t* Bp = B + (size_t)(n0 + br) * K + kbeg + bc;

  f32x4 acc[4][2];
#pragma unroll
  for (int i = 0; i < 4; ++i)
#pragma unroll
    for (int j = 0; j < 2; ++j) acc[i][j] = f32x4{0.f, 0.f, 0.f, 0.f};

  const int wm = (w & 3) * 64;
  const int wn = (w >> 2) * 32;
  const int fr = lane & 15;
  const int kq = (lane >> 4) * 8;

  for (int s = 0; s < nt; ++s) {
    bf16x8 a0 = *(const bf16x8*)(Ap + s * 64);
    bf16x8 a1 = *(const bf16x8*)(Ap + s * 64 + 8);
    bf16x8 b0 = *(const bf16x8*)(Bp + s * 64);
    __syncthreads();
    *(bf16x8*)&As[ar][ac] = a0;
    *(bf16x8*)&As[ar][ac + 8] = a1;
    *(bf16x8*)&Bs[br][bc] = b0;
    __syncthreads();
#pragma unroll
    for (int kk = 0; kk < 64; kk += 32) {
      bf16x8 af[4], bg[2];
#pragma unroll
      for (int i = 0; i < 4; ++i)
        af[i] = *(const bf16x8*)&As[wm + 16 * i + fr][kk + kq];
#pragma unroll
      for (int j = 0; j < 2; ++j)
        bg[j] = *(const bf16x8*)&Bs[wn + 16 * j + fr][kk + kq];
#pragma unroll
      for (int i = 0; i < 4; ++i)
#pragma unroll
        for (int j = 0; j < 2; ++j)
          acc[i][j] = __builtin_amdgcn_mfma_f32_16x16x32_bf16(af[i], bg[j], acc[i][j], 0, 0, 0);
    }
  }

  bf16_t* Cz = Cpart + (size_t)blockIdx.y * 256 * N;
  const int rh = (lane >> 4) * 4, col = lane & 15;
#pragma unroll
  for (int i = 0; i < 4; ++i)
#pragma unroll
    for (int j = 0; j < 2; ++j)
#pragma unroll
      for (int rr = 0; rr < 4; ++rr)
        Cz[(size_t)(wm + 16 * i + rh + rr) * N + n0 + wn + 16 * j + col] =
            (bf16_t)acc[i][j][rr];
}

// ============================================================================
// gemm_wide_s: simple 256x128 variant, A f32, B f32 (qb GEMM). Grid: (N/128,S)
// ============================================================================
__global__ __launch_bounds__(1024) void gemm_wide_s(
    const float* __restrict__ A, const float* __restrict__ B,
    bf16_t* __restrict__ Cpart, int N, int K, int KS) {
  __shared__ bf16_t As[256][72];
  __shared__ bf16_t Bs[128][72];
  const int t = threadIdx.x;
  const int lane = t & 63;
  const int w = t >> 6;
  const int n0 = blockIdx.x * 128;
  const int kbeg = blockIdx.y * KS;
  const int nt = KS >> 6;
  const int ar = t >> 2, ac = (t & 3) * 16;
  const int br = t >> 3, bc = (t & 7) * 8;
  const float* Ap = A + (size_t)ar * K + kbeg + ac;
  const float* Bp = B + (size_t)(n0 + br) * K + kbeg + bc;

  f32x4 acc[4][2];
#pragma unroll
  for (int i = 0; i < 4; ++i)
#pragma unroll
    for (int j = 0; j < 2; ++j) acc[i][j] = f32x4{0.f, 0.f, 0.f, 0.f};

  const int wm = (w & 3) * 64;
  const int wn = (w >> 2) * 32;
  const int fr = lane & 15;
  const int kq = (lane >> 4) * 8;

  for (int s = 0; s < nt; ++s) {
    float4 av[4], bv[2];
#pragma unroll
    for (int i = 0; i < 4; ++i) av[i] = *(const float4*)(Ap + s * 64 + 4 * i);
#pragma unroll
    for (int i = 0; i < 2; ++i) bv[i] = *(const float4*)(Bp + s * 64 + 4 * i);
    __syncthreads();
    {
      bf16x8 wa0, wa1, wb;
      wa0[0] = (bf16_t)av[0].x; wa0[1] = (bf16_t)av[0].y; wa0[2] = (bf16_t)av[0].z; wa0[3] = (bf16_t)av[0].w;
      wa0[4] = (bf16_t)av[1].x; wa0[5] = (bf16_t)av[1].y; wa0[6] = (bf16_t)av[1].z; wa0[7] = (bf16_t)av[1].w;
      wa1[0] = (bf16_t)av[2].x; wa1[1] = (bf16_t)av[2].y; wa1[2] = (bf16_t)av[2].z; wa1[3] = (bf16_t)av[2].w;
      wa1[4] = (bf16_t)av[3].x; wa1[5] = (bf16_t)av[3].y; wa1[6] = (bf16_t)av[3].z; wa1[7] = (bf16_t)av[3].w;
      wb[0] = (bf16_t)bv[0].x; wb[1] = (bf16_t)bv[0].y; wb[2] = (bf16_t)bv[0].z; wb[3] = (bf16_t)bv[0].w;
      wb[4] = (bf16_t)bv[1].x; wb[5] = (bf16_t)bv[1].y; wb[6] = (bf16_t)bv[1].z; wb[7] = (bf16_t)bv[1].w;
      *(bf16x8*)&As[ar][ac] = wa0;
      *(bf16x8*)&As[ar][ac + 8] = wa1;
      *(bf16x8*)&Bs[br][bc] = wb;
    }
    __syncthreads();
#pragma unroll
    for (int kk = 0; kk < 64; kk += 32) {
      bf16x8 af[4], bg[2];
#pragma unroll
      for (int i = 0; i < 4; ++i)
        af[i] = *(const bf16x8*)&As[wm + 16 * i + fr][kk + kq];
#pragma unroll
      for (int j = 0; j < 2; ++j)
        bg[j] = *(const bf16x8*)&Bs[wn + 16 * j + fr][kk + kq];
#pragma unroll
      for (int i = 0; i < 4; ++i)
#pragma unroll
        for (int j = 0; j < 2; ++j)
          acc[i][j] = __builtin_amdgcn_mfma_f32_16x16x32_bf16(af[i], bg[j], acc[i][j], 0, 0, 0);
    }
  }

  bf16_t* Cz = Cpart + (size_t)blockIdx.y * 256 * N;
  const int rh = (lane >> 4) * 4, col = lane & 15;
#pragma unroll
  for (int i = 0; i < 4; ++i)
#pragma unroll
    for (int j = 0; j < 2; ++j)
#pragma unroll
      for (int rr = 0; rr < 4; ++rr)
        Cz[(size_t)(wm + 16 * i + rh + rr) * N + n0 + wn + 16 * j + col] =
            (bf16_t)acc[i][j][rr];
}

// ============================================================================
// gemm_small (64x64 tile) -- qproj GEMM. A bf16, B f32, f32 split-K partials.
// ============================================================================
__global__ __launch_bounds__(256) void gemm_small(
    const bf16_t* __restrict__ A16, const float* __restrict__ B32, float* __restrict__ Cv,
    int M, int N, int K, int KS, int S) {
  __shared__ bf16_t As[64][72];
  __shared__ bf16_t Bs[64][72];
  const int t = threadIdx.x;
  const int lane = t & 63;
  const int w = t >> 6;
  const int s = blockIdx.z;
  const int n0 = blockIdx.x * 64;
  const int m0 = blockIdx.y * 64;
  const int kbeg = s * KS;

  f32x4 acc[2][2];
#pragma unroll
  for (int i = 0; i < 2; ++i)
#pragma unroll
    for (int j = 0; j < 2; ++j) acc[i][j] = f32x4{0.f, 0.f, 0.f, 0.f};

  const int wm = (w & 1) * 32, wn = (w >> 1) * 32;
  const int fr = lane & 15;
  const int kq = (lane >> 4) * 8;

  for (int k0 = kbeg; k0 < kbeg + KS; k0 += 64) {
    bf16x8 a8[2];
    float4 b4[4];
    {
      const int rr = t >> 2, c8 = (t & 3) * 8;
#pragma unroll
      for (int i = 0; i < 2; ++i)
        a8[i] = *(const bf16x8*)(A16 + (size_t)(m0 + rr) * K + k0 + c8 + 32 * i);
    }
    {
      const int rr = t >> 4, c4 = (t & 15) * 4;
#pragma unroll
      for (int i = 0; i < 4; ++i)
        b4[i] = *(const float4*)(B32 + (size_t)(n0 + rr + 16 * i) * K + k0 + c4);
    }
    __syncthreads();
    {
      const int rr = t >> 2, c8 = (t & 3) * 8;
#pragma unroll
      for (int i = 0; i < 2; ++i) *(bf16x8*)&As[rr][c8 + 32 * i] = a8[i];
    }
    {
      const int rr = t >> 4, c4 = (t & 15) * 4;
#pragma unroll
      for (int i = 0; i < 4; ++i) {
        bf16x4 v = {(bf16_t)b4[i].x, (bf16_t)b4[i].y, (bf16_t)b4[i].z, (bf16_t)b4[i].w};
        *(bf16x4*)&Bs[rr + 16 * i][c4] = v;
      }
    }
    __syncthreads();
#pragma unroll
    for (int kk = 0; kk < 64; kk += 32) {
      bf16x8 af[2], bg[2];
#pragma unroll
      for (int i = 0; i < 2; ++i) {
        af[i] = *(const bf16x8*)&As[wm + 16 * i + fr][kk + kq];
        bg[i] = *(const bf16x8*)&Bs[wn + 16 * i + fr][kk + kq];
      }
#pragma unroll
      for (int i = 0; i < 2; ++i)
#pragma unroll
        for (int j = 0; j < 2; ++j)
          acc[i][j] = __builtin_amdgcn_mfma_f32_16x16x32_bf16(af[i], bg[j], acc[i][j], 0, 0, 0);
    }
    __syncthreads();
  }

  const int rh = (lane >> 4) * 4;
  const int col = lane & 15;
#pragma unroll
  for (int i = 0; i < 2; ++i)
#pragma unroll
    for (int j = 0; j < 2; ++j)
#pragma unroll
      for (int rr = 0; rr < 4; ++rr)
        Cv[(size_t)s * M * N + (size_t)(m0 + wm + 16 * i + rh + rr) * N + n0 + wn + 16 * j + col] =
            acc[i][j][rr];
}

// ============================================================================
// gemm_attn: per-batch C(128,4096)bf16 = A(128,256)f32 @ B(256,4096)f32
// ============================================================================
__global__ __launch_bounds__(512) void gemm_attn(
    const float* __restrict__ A, const float* __restrict__ B, bf16_t* __restrict__ C) {
  __shared__ bf16_t As[128][72];
  __shared__ bf16_t Bs[64][72];  // Bs[n][k]
  const int t = threadIdx.x;
  const int lane = t & 63;
  const int w = t >> 6;
  const int b = blockIdx.y;
  const int n0 = blockIdx.x * 64;
  const float* Ab = A + (size_t)b * 32768;
  const float* Bb = B + (size_t)b * 1048576;

  f32x4 acc[2][2];
#pragma unroll
  for (int i = 0; i < 2; ++i)
#pragma unroll
    for (int j = 0; j < 2; ++j) acc[i][j] = f32x4{0.f, 0.f, 0.f, 0.f};

  const int wm = (w & 3) * 32;
  const int wn = (w >> 2) * 32;
  const int fr = lane & 15;
  const int kq = (lane >> 4) * 8;

  for (int k0 = 0; k0 < 256; k0 += 64) {
    const int r = t >> 2, c4 = (t & 3) * 16;
    float4 a4[4];
#pragma unroll
    for (int i = 0; i < 4; ++i)
      a4[i] = *(const float4*)(Ab + (size_t)r * 256 + k0 + c4 + 4 * i);
    const int kr = t >> 3, nc = (t & 7) * 8;
    float4 b4[2];
#pragma unroll
    for (int i = 0; i < 2; ++i)
      b4[i] = *(const float4*)(Bb + (size_t)(k0 + kr) * 4096 + n0 + nc + 4 * i);
    __syncthreads();
#pragma unroll
    for (int i = 0; i < 4; ++i) {
      bf16x4 v = {(bf16_t)a4[i].x, (bf16_t)a4[i].y, (bf16_t)a4[i].z, (bf16_t)a4[i].w};
      *(bf16x4*)&As[r][c4 + 4 * i] = v;
    }
#pragma unroll
    for (int i = 0; i < 2; ++i) {
      Bs[nc + 4 * i + 0][kr] = (bf16_t)b4[i].x;
      Bs[nc + 4 * i + 1][kr] = (bf16_t)b4[i].y;
      Bs[nc + 4 * i + 2][kr] = (bf16_t)b4[i].z;
      Bs[nc + 4 * i + 3][kr] = (bf16_t)b4[i].w;
    }
    __syncthreads();
#pragma unroll
    for (int kk = 0; kk < 64; kk += 32) {
      bf16x8 af[2], bg[2];
#pragma unroll
      for (int i = 0; i < 2; ++i) {
        af[i] = *(const bf16x8*)&As[wm + 16 * i + fr][kk + kq];
        bg[i] = *(const bf16x8*)&Bs[wn + 16 * i + fr][kk + kq];
      }
#pragma unroll
      for (int i = 0; i < 2; ++i)
#pragma unroll
        for (int j = 0; j < 2; ++j)
          acc[i][j] = __builtin_amdgcn_mfma_f32_16x16x32_bf16(af[i], bg[j], acc[i][j], 0, 0, 0);
    }
    __syncthreads();
  }

  bf16_t* Cb = C + (size_t)b * 524288;
  const int rh = (lane >> 4) * 4, col = lane & 15;
#pragma unroll
  for (int i = 0; i < 2; ++i)
#pragma unroll
    for (int j = 0; j < 2; ++j)
#pragma unroll
      for (int rr = 0; rr < 4; ++rr)
        Cb[(size_t)(wm + 16 * i + rh + rr) * 4096 + n0 + wn + 16 * j + col] =
            (bf16_t)acc[i][j][rr];
}

// ---------------- fused partF reduce + bias + silu -> fusb, then LN -> lnf ---
__global__ __launch_bounds__(256) void red_ln(
    const bf16_t* __restrict__ partF, int S,
    const float* __restrict__ bias,
    const float* __restrict__ g, const float* __restrict__ bta,
    bf16_t* __restrict__ fusb, bf16_t* __restrict__ lnf) {
  __shared__ float tmp[4];
  const int row = blockIdx.x;
  const int t = threadIdx.x;
  const long i0 = t * 16;
  float a[16];
#pragma unroll
  for (int j = 0; j < 16; ++j) a[j] = 0.f;
  for (int s = 0; s < S; ++s) {
    const bf16_t* p = partF + (size_t)s * 1048576 + (size_t)row * 4096 + i0;
    bf16x8 v0 = *(const bf16x8*)(p);
    bf16x8 v1 = *(const bf16x8*)(p + 8);
#pragma unroll
    for (int j = 0; j < 8; ++j) { a[j] += (float)v0[j]; a[8 + j] += (float)v1[j]; }
  }
#pragma unroll
  for (int j = 0; j < 16; ++j) a[j] = silu_f(a[j] + bias[i0 + j]);
  {
    bf16x8 o0, o1;
#pragma unroll
    for (int j = 0; j < 8; ++j) { o0[j] = (bf16_t)a[j]; o1[j] = (bf16_t)a[8 + j]; }
    *(bf16x8*)(fusb + (size_t)row * 4096 + i0) = o0;
    *(bf16x8*)(fusb + (size_t)row * 4096 + i0 + 8) = o1;
  }
  float s1 = 0.f, s2 = 0.f;
#pragma unroll
  for (int j = 0; j < 16; ++j) { s1 += a[j]; s2 += a[j] * a[j]; }
  s1 = block_sum(s1, tmp);
  s2 = block_sum(s2, tmp);
  const float mu = s1 / 4096.f;
  const float inv = rsqrtf(s2 / 4096.f - mu * mu + EPS);
  bf16x8 o0, o1;
#pragma unroll
  for (int j = 0; j < 8; ++j) {
    o0[j] = (bf16_t)((a[j] - mu) * inv * g[i0 + j] + bta[i0 + j]);
    o1[j] = (bf16_t)((a[8 + j] - mu) * inv * g[i0 + 8 + j] + bta[i0 + 8 + j]);
  }
  *(bf16x8*)(lnf + (size_t)row * 4096 + i0) = o0;
  *(bf16x8*)(lnf + (size_t)row * 4096 + i0 + 8) = o1;
}

// ---------------- fused partQ-reduce + LayerNorm(concat(refv, qb)) -> bf16 ---
__global__ __launch_bounds__(256) void ln_fuse(
    const float* __restrict__ refv, const bf16_t* __restrict__ partQ, int S,
    const float* __restrict__ g, const float* __restrict__ bta, bf16_t* __restrict__ Y) {
  __shared__ float tmp[4];
  const int row = blockIdx.x;
  const int t = threadIdx.x;
  const long i0 = t * 16;
  float q[16];
#pragma unroll
  for (int j = 0; j < 16; ++j) q[j] = 0.f;
  for (int s = 0; s < S; ++s) {
    const bf16_t* p = partQ + (size_t)s * 1048576 + (size_t)row * 4096 + i0;
    bf16x8 v0 = *(const bf16x8*)(p);
    bf16x8 v1 = *(const bf16x8*)(p + 8);
#pragma unroll
    for (int j = 0; j < 8; ++j) { q[j] += (float)v0[j]; q[8 + j] += (float)v1[j]; }
  }
  const float* xr = refv + (size_t)row * 4096 + i0;
  float r[16];
#pragma unroll
  for (int j = 0; j < 4; ++j) {
    float4 v = *(const float4*)(xr + 4 * j);
    r[4 * j] = v.x; r[4 * j + 1] = v.y; r[4 * j + 2] = v.z; r[4 * j + 3] = v.w;
  }
  float s1 = 0.f, s2 = 0.f;
#pragma unroll
  for (int j = 0; j < 16; ++j) { s1 += r[j] + q[j]; s2 += r[j] * r[j] + q[j] * q[j]; }
  s1 = block_sum(s1, tmp);
  s2 = block_sum(s2, tmp);
  const float mu = s1 / 8192.f;
  const float inv = rsqrtf(s2 / 8192.f - mu * mu + EPS);
  bf16_t* y = Y + (size_t)row * 8192;
  bf16x8 o0, o1;
#pragma unroll
  for (int j = 0; j < 8; ++j) {
    o0[j] = (bf16_t)((r[j] - mu) * inv * g[i0 + j] + bta[i0 + j]);
    o1[j] = (bf16_t)((r[8 + j] - mu) * inv * g[i0 + 8 + j] + bta[i0 + 8 + j]);
  }
  *(bf16x8*)(y + i0) = o0;
  *(bf16x8*)(y + i0 + 8) = o1;
#pragma unroll
  for (int j = 0; j < 8; ++j) {
    o0[j] = (bf16_t)((q[j] - mu) * inv * g[4096 + i0 + j] + bta[4096 + i0 + j]);
    o1[j] = (bf16_t)((q[8 + j] - mu) * inv * g[4096 + i0 + 8 + j] + bta[4096 + i0 + 8 + j]);
  }
  *(bf16x8*)(y + 4096 + i0) = o0;
  *(bf16x8*)(y + 4096 + i0 + 8) = o1;
}

// ---------------- fused part8-reduce + QW ----------------
__global__ __launch_bounds__(256) void qw_fuse(
    const float* __restrict__ part8, const float* __restrict__ kW, float* __restrict__ QW) {
  __shared__ float q[256];
  const int bk = blockIdx.x;
  const int c = threadIdx.x;
  float sq = 0.f;
#pragma unroll
  for (int s = 0; s < 8; ++s) sq += part8[(size_t)s * 65536 + (size_t)bk * 256 + c];
  q[c] = 0.125f * sq;
  __syncthreads();
#pragma unroll
  for (int h = 0; h < 4; ++h) {
    float s = 0.f;
#pragma unroll 8
    for (int d = 0; d < 64; ++d)
      s += q[(h << 6) + d] * kW[(size_t)(((h << 6) + d) << 8) + c];
    QW[((size_t)(bk * 4 + h) << 8) + c] = s;
  }
}

// ---------------- fused conv1(4->4,silu) + conv2(4->1) + bilinear up ----------
__global__ __launch_bounds__(256) void conv_fused(
    const bf16_t* __restrict__ X, const float* __restrict__ W1,
    const float* __restrict__ B1, const float* __restrict__ W2,
    const float* __restrict__ B2, float* __restrict__ O) {
  __shared__ bf16_t lg[16384];
  __shared__ bf16_t mid[16384];
  __shared__ float lg64[4096];
  __shared__ float wsh[180];
  const int t = threadIdx.x;
  const size_t base = (size_t)blockIdx.x * 16384;
#pragma unroll
  for (int i = 0; i < 8; ++i) {
    int o = (i * 256 + t) * 8;
    *(bf16x8*)&lg[o] = *(const bf16x8*)(X + base + o);
  }
  if (t < 144) wsh[t] = W1[t];
  else if (t < 180) wsh[t] = W2[t - 144];
  __syncthreads();
  const int px0 = (t & 15) * 4, py0 = (t >> 4) * 4;
  {
    float acc1[4][16];
#pragma unroll
    for (int oc = 0; oc < 4; ++oc) {
      float bb = B1[oc];
#pragma unroll
      for (int p = 0; p < 16; ++p) acc1[oc][p] = bb;
    }
#pragma unroll
    for (int c = 0; c < 4; ++c) {
      float p[6][6];
#pragma unroll
      for (int yy = 0; yy < 6; ++yy) {
        int gy = py0 + yy - 1;
#pragma unroll
        for (int xx = 0; xx < 6; ++xx) {
          int gx = px0 + xx - 1;
          p[yy][xx] = ((unsigned)gy < 64u && (unsigned)gx < 64u)
                          ? (float)lg[c * 4096 + gy * 64 + gx] : 0.f;
        }
      }
#pragma unroll
      for (int oc = 0; oc < 4; ++oc) {
        float wr[9];
#pragma unroll
        for (int k = 0; k < 9; ++k) wr[k] = wsh[oc * 36 + c * 9 + k];
#pragma unroll
        for (int y = 0; y < 4; ++y)
#pragma unroll
          for (int x = 0; x < 4; ++x)
            acc1[oc][y * 4 + x] +=
                wr[0] * p[y][x] + wr[1] * p[y][x + 1] + wr[2] * p[y][x + 2]
              + wr[3] * p[y + 1][x] + wr[4] * p[y + 1][x + 1] + wr[5] * p[y + 1][x + 2]
              + wr[6] * p[y + 2][x] + wr[7] * p[y + 2][x + 1] + wr[8] * p[y + 2][x + 2];
      }
    }
#pragma unroll
    for (int oc = 0; oc < 4; ++oc)
#pragma unroll
      for (int y = 0; y < 4; ++y) {
        bf16x4 o;
#pragma unroll
        for (int x = 0; x < 4; ++x) o[x] = (bf16_t)silu_f(acc1[oc][y * 4 + x]);
        *(bf16x4*)&mid[oc * 4096 + (py0 + y) * 64 + px0] = o;
      }
  }
  __syncthreads();
  {
    float acc2[16];
    float bb = B2[0];
#pragma unroll
    for (int p = 0; p < 16; ++p) acc2[p] = bb;
#pragma unroll
    for (int c = 0; c < 4; ++c) {
      float p[6][6];
#pragma unroll
      for (int yy = 0; yy < 6; ++yy) {
        int gy = py0 + yy - 1;
#pragma unroll
        for (int xx = 0; xx < 6; ++xx) {
          int gx = px0 + xx - 1;
          p[yy][xx] = ((unsigned)gy < 64u && (unsigned)gx < 64u)
                          ? (float)mid[c * 4096 + gy * 64 + gx] : 0.f;
        }
      }
      float wr[9];
#pragma unroll
      for (int k = 0; k < 9; ++k) wr[k] = wsh[144 + c * 9 + k];
#pragma unroll
      for (int y = 0; y < 4; ++y)
#pragma unroll
        for (int x = 0; x < 4; ++x)
          acc2[y * 4 + x] +=
              wr[0] * p[y][x] + wr[1] * p[y][x + 1] + wr[2] * p[y][x + 2]
            + wr[3] * p[y + 1][x] + wr[4] * p[y + 1][x + 1] + wr[5] * p[y + 1][x + 2]
            + wr[6] * p[y + 2][x] + wr[7] * p[y + 2][x + 1] + wr[8] * p[y + 2][x + 2];
    }
#pragma unroll
    for (int y = 0; y < 4; ++y)
#pragma unroll
      for (int x = 0; x < 4; ++x) lg64[(py0 + y) * 64 + px0 + x] = acc2[y * 4 + x];
  }
  __syncthreads();
  float* Ob = O + (size_t)blockIdx.x * 65536;
  for (int rr = 0; rr < 64; ++rr) {
    int p4 = rr * 256 + t;
    int oy = p4 >> 6, ox0 = (p4 & 63) * 4;
    float sy = oy * 0.25f - 0.375f;
    int y0 = (int)floorf(sy);
    float wy = sy - (float)y0;
    int y1 = min(y0 + 1, 63); y0 = max(y0, 0);
    const float* r0 = &lg64[y0 * 64];
    const float* r1 = &lg64[y1 * 64];
    float4 o;
#pragma unroll
    for (int q = 0; q < 4; ++q) {
      int ox = ox0 + q;
      float sx = ox * 0.25f - 0.375f;
      int x0 = (int)floorf(sx);
      float wx = sx - (float)x0;
      int x1 = min(x0 + 1, 63); x0 = max(x0, 0);
      float v0 = r0[x0] + wx * (r0[x1] - r0[x0]);
      float v1 = r1[x0] + wx * (r1[x1] - r1[x0]);
      ((float*)&o)[q] = v0 + wy * (v1 - v0);
    }
    *(float4*)(Ob + oy * 256 + ox0) = o;
  }
}

// ---------------- fused partC reduce + bias + silu + dot(w2) + b2 ------------
__global__ __launch_bounds__(256) void conf_fuse(
    const bf16_t* __restrict__ partC, int S,
    const float* __restrict__ cb1, const float* __restrict__ w2,
    const float* __restrict__ b2, float* __restrict__ out) {
  __shared__ float tmp[4];
  const int row = blockIdx.x;
  const int t = threadIdx.x;
  const long i0 = t * 8;
  float a[8];
#pragma unroll
  for (int j = 0; j < 8; ++j) a[j] = 0.f;
  for (int s = 0; s < S; ++s) {
    bf16x8 v = *(const bf16x8*)(partC + (size_t)s * 524288 + (size_t)row * 2048 + i0);
#pragma unroll
    for (int j = 0; j < 8; ++j) a[j] += (float)v[j];
  }
  float dot = 0.f;
#pragma unroll
  for (int j = 0; j < 8; ++j) dot += silu_f(a[j] + cb1[i0 + j]) * w2[i0 + j];
  dot = block_sum(dot, tmp);
  if (t == 0) out[row] = dot + b2[0];
}

extern "C" void kernel_launch(void* const* d_in, const int* in_sizes, int n_in,
                              void* d_out, int out_size, void* d_ws, size_t ws_size,
                              hipStream_t stream) {
  const float* img    = (const float*)d_in[0];
  const float* refv   = (const float*)d_in[1];
  const float* qs     = (const float*)d_in[2];
  const float* qpw    = (const float*)d_in[3];
  const float* kpw    = (const float*)d_in[4];
  const float* fw1    = (const float*)d_in[5];
  const float* fb1    = (const float*)d_in[6];
  const float* fw2    = (const float*)d_in[7];
  const float* fb2    = (const float*)d_in[8];
  const float* qbw    = (const float*)d_in[9];
  const float* rlg    = (const float*)d_in[10];
  const float* rlb    = (const float*)d_in[11];
  const float* rlw    = (const float*)d_in[12];
  const float* rlbias = (const float*)d_in[13];
  const float* clg    = (const float*)d_in[14];
  const float* clb    = (const float*)d_in[15];
  const float* cw1    = (const float*)d_in[16];
  const float* cb1    = (const float*)d_in[17];
  const float* cw2    = (const float*)d_in[18];
  const float* cb2    = (const float*)d_in[19];
  float* out = (float*)d_out;
  char* W = (char*)d_ws;

  // --- workspace layout (bytes); disjoint lifetimes per region ---
  bf16_t* partQ = (bf16_t*)(W + 0);          // 16.8 MB
  bf16_t* partF = (bf16_t*)(W + 0);          // 33.6 MB (partQ dead)
  bf16_t* l64hb = (bf16_t*)(W + 0);          //  8.4 MB (partF dead)
  bf16_t* partC = (bf16_t*)(W + 0);          // 16.8 MB (l64hb dead)
  bf16_t* catln = (bf16_t*)(W + 33554432);   //  4.2 MB
  bf16_t* fusb  = (bf16_t*)(W + 37748736);   //  2.1 MB
  bf16_t* lnf   = (bf16_t*)(W + 39845888);   //  2.1 MB
  float*  part8 = (float*)(W + 41943040);    //  2.1 MB
  float*  QW    = (float*)(W + 44040192);    //  1.1 MB
  bf16_t* rlwb  = (bf16_t*)(W + 67108864);   // 67.1 MB (cast rlw, whole launch)
  bf16_t* cw1b  = (bf16_t*)(W + 150994944);  // 16.8 MB (cast cw1, whole launch)

  dim3 b256(256);

  // 0a. rlwb = bf16(rlw)   (33.55M elts)
  cast_w<<<dim3(4096), b256, 0, stream>>>(rlw, rlwb, 4194304L);
  // 0b. cw1b = bf16(cw1)   (8.39M elts)
  cast_w<<<dim3(4096), b256, 0, stream>>>(cw1, cw1b, 1048576L);
  // 1. qb GEMM (split-K x8, nt=1): partQ[s] = qs @ qbw^T chunk
  gemm_wide_s<<<dim3(32, 8), dim3(1024), 0, stream>>>(qs, qbw, partQ, 4096, 512, 64);
  // 2. catln = LN(concat(refv, sum partQ)) -> bf16
  ln_fuse<<<dim3(256), b256, 0, stream>>>(refv, partQ, 8, rlg, rlb, catln);
  // 3. fused GEMM (all-bf16 full-M, split-K x16): partF[s] = catln @ rlwb^T
  gemm_wb<<<dim3(32, 16), dim3(1024), 0, stream>>>(catln, rlwb, partF, 4096, 8192, 512);
  // 4. fusb = silu(sum partF + bias); lnf = LN(fusb)
  red_ln<<<dim3(256), b256, 0, stream>>>(partF, 16, rlbias, clg, clb, fusb, lnf);
  // 5. qproj GEMM (split-K x8): part8[s] = fusb @ qpw^T chunk
  gemm_small<<<dim3(4, 4, 8), b256, 0, stream>>>(fusb, qpw, part8, 256, 256, 4096, 512, 8);
  // 6. QW = per-head (0.125 * sum part8) @ k_proj
  qw_fuse<<<dim3(256), b256, 0, stream>>>(part8, kpw, QW);
  // 7. logits (full-M): l64hb[b] = QW_b @ img_b
  gemm_attn<<<dim3(64, 8), dim3(512), 0, stream>>>(QW, img, l64hb);
  // 8. out = upsample(conv2(silu(conv1(l64hb))))
  conv_fused<<<dim3(256), b256, 0, stream>>>(l64hb, fw1, fb1, fw2, fb2, out);
  // 9. cfh GEMM (all-bf16 full-M, split-K x16): partC[s] = lnf @ cw1b^T
  gemm_wb<<<dim3(16, 16), dim3(1024), 0, stream>>>(lnf, cw1b, partC, 2048, 4096, 256);
  // 10. conf out = silu(sum partC + cb1) . w2 + b2
  conf_fuse<<<dim3(256), b256, 0, stream>>>(partC, 16, cb1, cw2, cb2, out + 16777216);
}

// Round 17
// 175.053 us; speedup vs baseline: 1.2039x; 1.2039x over previous
//
#include <hip/hip_runtime.h>

#define EPS 1e-5f

typedef __bf16 bf16_t;
typedef __bf16 bf16x8 __attribute__((ext_vector_type(8)));
typedef __bf16 bf16x4 __attribute__((ext_vector_type(4)));
typedef float f32x4 __attribute__((ext_vector_type(4)));

__device__ __forceinline__ float silu_f(float x) { return x / (1.f + __expf(-x)); }

__device__ __forceinline__ void gll16(const void* g, void* l) {
  __builtin_amdgcn_global_load_lds(
      (const __attribute__((address_space(1))) unsigned int*)g,
      (__attribute__((address_space(3))) unsigned int*)l, 16, 0, 0);
}

// ---------------- block reduction (256 threads = 4 waves) ----------------
__device__ __forceinline__ float block_sum(float v, float* tmp) {
#pragma unroll
  for (int off = 32; off > 0; off >>= 1) v += __shfl_down(v, off);
  __syncthreads();
  if ((threadIdx.x & 63) == 0) tmp[threadIdx.x >> 6] = v;
  __syncthreads();
  return tmp[0] + tmp[1] + tmp[2] + tmp[3];
}

// ============================================================================
// gemm_gll (r10 best-known): Cpart[z](bf16) = A(256,K)bf16 @ B(N,K)^T f32.
// tile 256x128, BK=64, 1024 threads (16 waves, wave-tile 64x32).
// Double-buffered LINEAR LDS; staging via global_load_lds width=16 (zero VGPR,
// ~8KB/wave in flight). XOR chunk-swizzle on the GLOBAL source + on the
// ds_read side; LDS dest linear. Counted vmcnt(4) mid-loop (never 0).
// Grid: (N/128, S), KS = K/S, nt = KS/64 >= 1.
// ============================================================================
__global__ __launch_bounds__(1024) void gemm_gll(
    const bf16_t* __restrict__ A, const float* __restrict__ B,
    bf16_t* __restrict__ Cpart, int N, int K, int KS) {
  __shared__ bf16_t AsL[2][16384];  // 256 rows x 64 bf16 (128 B rows, 8 chunks)
  __shared__ float BsL[2][8192];    // 128 rows x 64 f32  (256 B rows, 16 chunks)
  const int t = threadIdx.x;
  const int lane = t & 63;
  const int w = t >> 6;  // 0..15
  const int n0 = blockIdx.x * 128;
  const int kbeg = blockIdx.y * KS;
  const int nt = KS >> 6;

  const int arow0 = 16 * w + (lane >> 3);
  const int adch = (lane & 7) ^ (lane >> 3);
  const bf16_t* gA = A + (size_t)arow0 * K + kbeg + adch * 8;
  const bf16_t* gA1 = gA + (size_t)8 * K;
  const int brow0 = 8 * w + (lane >> 4);
  const int brow1 = brow0 + 4;
  const int bd0 = (lane & 15) ^ (brow0 & 15);
  const int bd1 = (lane & 15) ^ (brow1 & 15);
  const float* gB0 = B + (size_t)(n0 + brow0) * K + kbeg + bd0 * 4;
  const float* gB1 = B + (size_t)(n0 + brow1) * K + kbeg + bd1 * 4;

  f32x4 acc[4][2];
#pragma unroll
  for (int i = 0; i < 4; ++i)
#pragma unroll
    for (int j = 0; j < 2; ++j) acc[i][j] = f32x4{0.f, 0.f, 0.f, 0.f};

  const int wm = (w & 3) * 64;
  const int wn = (w >> 2) * 32;
  const int fr = lane & 15;
  const int kq = (lane >> 4) * 8;

  auto ISSUE = [&](int s, int p) {
    const int koff = s * 64;
    char* ab = (char*)&AsL[p][0] + 2 * w * 1024;
    char* bb = (char*)&BsL[p][0] + 2 * w * 1024;
    gll16(gA + koff, ab);
    gll16(gA1 + koff, ab + 1024);
    gll16(gB0 + koff, bb);
    gll16(gB1 + koff, bb + 1024);
  };

  auto COMPUTE = [&](int p) {
    const char* Ab = (const char*)&AsL[p][0];
    const char* Bb = (const char*)&BsL[p][0];
#pragma unroll
    for (int kk = 0; kk < 64; kk += 32) {
      const int col = kk + kq;
      bf16x8 af[4], bg[2];
#pragma unroll
      for (int i = 0; i < 4; ++i) {
        const int ra = wm + 16 * i + fr;
        const int sa = (col >> 3) ^ (ra & 7);
        af[i] = *(const bf16x8*)(Ab + ra * 128 + sa * 16);
      }
#pragma unroll
      for (int j = 0; j < 2; ++j) {
        const int rb = wn + 16 * j + fr;
        const int c0 = col >> 2;
        const int s0 = c0 ^ (rb & 15);
        const int s1 = (c0 + 1) ^ (rb & 15);
        f32x4 u0 = *(const f32x4*)(Bb + rb * 256 + s0 * 16);
        f32x4 u1 = *(const f32x4*)(Bb + rb * 256 + s1 * 16);
        bf16x8 bv;
        bv[0] = (bf16_t)u0[0]; bv[1] = (bf16_t)u0[1];
        bv[2] = (bf16_t)u0[2]; bv[3] = (bf16_t)u0[3];
        bv[4] = (bf16_t)u1[0]; bv[5] = (bf16_t)u1[1];
        bv[6] = (bf16_t)u1[2]; bv[7] = (bf16_t)u1[3];
        bg[j] = bv;
      }
#pragma unroll
      for (int i = 0; i < 4; ++i)
#pragma unroll
        for (int j = 0; j < 2; ++j)
          acc[i][j] = __builtin_amdgcn_mfma_f32_16x16x32_bf16(af[i], bg[j], acc[i][j], 0, 0, 0);
    }
  };

#define SB __builtin_amdgcn_sched_barrier(0);

  ISSUE(0, 0);
  if (nt > 1) ISSUE(1, 1);
  for (int s = 0; s < nt; ++s) {
    const int p = s & 1;
    if (s + 1 < nt) {
      asm volatile("s_waitcnt vmcnt(4)" ::: "memory");
    } else {
      asm volatile("s_waitcnt vmcnt(0)" ::: "memory");
    }
    SB __builtin_amdgcn_s_barrier(); SB
    COMPUTE(p);
    if (s + 2 < nt) {
      asm volatile("s_waitcnt lgkmcnt(0)" ::: "memory");
      SB __builtin_amdgcn_s_barrier(); SB
      ISSUE(s + 2, p);
    }
  }
#undef SB

  bf16_t* Cz = Cpart + (size_t)blockIdx.y * 256 * N;
  const int rh = (lane >> 4) * 4, col = lane & 15;
#pragma unroll
  for (int i = 0; i < 4; ++i)
#pragma unroll
    for (int j = 0; j < 2; ++j)
#pragma unroll
      for (int rr = 0; rr < 4; ++rr)
        Cz[(size_t)(wm + 16 * i + rh + rr) * N + n0 + wn + 16 * j + col] =
            (bf16_t)acc[i][j][rr];
}

// ============================================================================
// gemm_wide_s: simple 256x128 variant, A f32 (qb GEMM). Grid: (N/128, S).
// ============================================================================
__global__ __launch_bounds__(1024) void gemm_wide_s(
    const float* __restrict__ A, const float* __restrict__ B,
    bf16_t* __restrict__ Cpart, int N, int K, int KS) {
  __shared__ bf16_t As[256][72];
  __shared__ bf16_t Bs[128][72];
  const int t = threadIdx.x;
  const int lane = t & 63;
  const int w = t >> 6;
  const int n0 = blockIdx.x * 128;
  const int kbeg = blockIdx.y * KS;
  const int nt = KS >> 6;
  const int ar = t >> 2, ac = (t & 3) * 16;
  const int br = t >> 3, bc = (t & 7) * 8;
  const float* Ap = A + (size_t)ar * K + kbeg + ac;
  const float* Bp = B + (size_t)(n0 + br) * K + kbeg + bc;

  f32x4 acc[4][2];
#pragma unroll
  for (int i = 0; i < 4; ++i)
#pragma unroll
    for (int j = 0; j < 2; ++j) acc[i][j] = f32x4{0.f, 0.f, 0.f, 0.f};

  const int wm = (w & 3) * 64;
  const int wn = (w >> 2) * 32;
  const int fr = lane & 15;
  const int kq = (lane >> 4) * 8;

  for (int s = 0; s < nt; ++s) {
    float4 av[4], bv[2];
#pragma unroll
    for (int i = 0; i < 4; ++i) av[i] = *(const float4*)(Ap + s * 64 + 4 * i);
#pragma unroll
    for (int i = 0; i < 2; ++i) bv[i] = *(const float4*)(Bp + s * 64 + 4 * i);
    __syncthreads();
    {
      bf16x8 wa0, wa1, wb;
      wa0[0] = (bf16_t)av[0].x; wa0[1] = (bf16_t)av[0].y; wa0[2] = (bf16_t)av[0].z; wa0[3] = (bf16_t)av[0].w;
      wa0[4] = (bf16_t)av[1].x; wa0[5] = (bf16_t)av[1].y; wa0[6] = (bf16_t)av[1].z; wa0[7] = (bf16_t)av[1].w;
      wa1[0] = (bf16_t)av[2].x; wa1[1] = (bf16_t)av[2].y; wa1[2] = (bf16_t)av[2].z; wa1[3] = (bf16_t)av[2].w;
      wa1[4] = (bf16_t)av[3].x; wa1[5] = (bf16_t)av[3].y; wa1[6] = (bf16_t)av[3].z; wa1[7] = (bf16_t)av[3].w;
      wb[0] = (bf16_t)bv[0].x; wb[1] = (bf16_t)bv[0].y; wb[2] = (bf16_t)bv[0].z; wb[3] = (bf16_t)bv[0].w;
      wb[4] = (bf16_t)bv[1].x; wb[5] = (bf16_t)bv[1].y; wb[6] = (bf16_t)bv[1].z; wb[7] = (bf16_t)bv[1].w;
      *(bf16x8*)&As[ar][ac] = wa0;
      *(bf16x8*)&As[ar][ac + 8] = wa1;
      *(bf16x8*)&Bs[br][bc] = wb;
    }
    __syncthreads();
#pragma unroll
    for (int kk = 0; kk < 64; kk += 32) {
      bf16x8 af[4], bg[2];
#pragma unroll
      for (int i = 0; i < 4; ++i)
        af[i] = *(const bf16x8*)&As[wm + 16 * i + fr][kk + kq];
#pragma unroll
      for (int j = 0; j < 2; ++j)
        bg[j] = *(const bf16x8*)&Bs[wn + 16 * j + fr][kk + kq];
#pragma unroll
      for (int i = 0; i < 4; ++i)
#pragma unroll
        for (int j = 0; j < 2; ++j)
          acc[i][j] = __builtin_amdgcn_mfma_f32_16x16x32_bf16(af[i], bg[j], acc[i][j], 0, 0, 0);
    }
    __syncthreads();
  }

  bf16_t* Cz = Cpart + (size_t)blockIdx.y * 256 * N;
  const int rh = (lane >> 4) * 4, col = lane & 15;
#pragma unroll
  for (int i = 0; i < 4; ++i)
#pragma unroll
    for (int j = 0; j < 2; ++j)
#pragma unroll
      for (int rr = 0; rr < 4; ++rr)
        Cz[(size_t)(wm + 16 * i + rh + rr) * N + n0 + wn + 16 * j + col] =
            (bf16_t)acc[i][j][rr];
}

// ============================================================================
// gemm_small (64x64 tile) -- qproj GEMM. A bf16, B f32, f32 split-K partials.
// ============================================================================
__global__ __launch_bounds__(256) void gemm_small(
    const bf16_t* __restrict__ A16, const float* __restrict__ B32, float* __restrict__ Cv,
    int M, int N, int K, int KS, int S) {
  __shared__ bf16_t As[64][72];
  __shared__ bf16_t Bs[64][72];
  const int t = threadIdx.x;
  const int lane = t & 63;
  const int w = t >> 6;
  const int s = blockIdx.z;
  const int n0 = blockIdx.x * 64;
  const int m0 = blockIdx.y * 64;
  const int kbeg = s * KS;

  f32x4 acc[2][2];
#pragma unroll
  for (int i = 0; i < 2; ++i)
#pragma unroll
    for (int j = 0; j < 2; ++j) acc[i][j] = f32x4{0.f, 0.f, 0.f, 0.f};

  const int wm = (w & 1) * 32, wn = (w >> 1) * 32;
  const int fr = lane & 15;
  const int kq = (lane >> 4) * 8;

  for (int k0 = kbeg; k0 < kbeg + KS; k0 += 64) {
    bf16x8 a8[2];
    float4 b4[4];
    {
      const int rr = t >> 2, c8 = (t & 3) * 8;
#pragma unroll
      for (int i = 0; i < 2; ++i)
        a8[i] = *(const bf16x8*)(A16 + (size_t)(m0 + rr) * K + k0 + c8 + 32 * i);
    }
    {
      const int rr = t >> 4, c4 = (t & 15) * 4;
#pragma unroll
      for (int i = 0; i < 4; ++i)
        b4[i] = *(const float4*)(B32 + (size_t)(n0 + rr + 16 * i) * K + k0 + c4);
    }
    __syncthreads();
    {
      const int rr = t >> 2, c8 = (t & 3) * 8;
#pragma unroll
      for (int i = 0; i < 2; ++i) *(bf16x8*)&As[rr][c8 + 32 * i] = a8[i];
    }
    {
      const int rr = t >> 4, c4 = (t & 15) * 4;
#pragma unroll
      for (int i = 0; i < 4; ++i) {
        bf16x4 v = {(bf16_t)b4[i].x, (bf16_t)b4[i].y, (bf16_t)b4[i].z, (bf16_t)b4[i].w};
        *(bf16x4*)&Bs[rr + 16 * i][c4] = v;
      }
    }
    __syncthreads();
#pragma unroll
    for (int kk = 0; kk < 64; kk += 32) {
      bf16x8 af[2], bg[2];
#pragma unroll
      for (int i = 0; i < 2; ++i) {
        af[i] = *(const bf16x8*)&As[wm + 16 * i + fr][kk + kq];
        bg[i] = *(const bf16x8*)&Bs[wn + 16 * i + fr][kk + kq];
      }
#pragma unroll
      for (int i = 0; i < 2; ++i)
#pragma unroll
        for (int j = 0; j < 2; ++j)
          acc[i][j] = __builtin_amdgcn_mfma_f32_16x16x32_bf16(af[i], bg[j], acc[i][j], 0, 0, 0);
    }
    __syncthreads();
  }

  const int rh = (lane >> 4) * 4;
  const int col = lane & 15;
#pragma unroll
  for (int i = 0; i < 2; ++i)
#pragma unroll
    for (int j = 0; j < 2; ++j)
#pragma unroll
      for (int rr = 0; rr < 4; ++rr)
        Cv[(size_t)s * M * N + (size_t)(m0 + wm + 16 * i + rh + rr) * N + n0 + wn + 16 * j + col] =
            acc[i][j][rr];
}

// ============================================================================
// gemm_attn: per-batch C(128,4096)bf16 = A(128,256)f32 @ B(256,4096)f32
// ============================================================================
__global__ __launch_bounds__(512) void gemm_attn(
    const float* __restrict__ A, const float* __restrict__ B, bf16_t* __restrict__ C) {
  __shared__ bf16_t As[128][72];
  __shared__ bf16_t Bs[64][72];  // Bs[n][k]
  const int t = threadIdx.x;
  const int lane = t & 63;
  const int w = t >> 6;
  const int b = blockIdx.y;
  const int n0 = blockIdx.x * 64;
  const float* Ab = A + (size_t)b * 32768;
  const float* Bb = B + (size_t)b * 1048576;

  f32x4 acc[2][2];
#pragma unroll
  for (int i = 0; i < 2; ++i)
#pragma unroll
    for (int j = 0; j < 2; ++j) acc[i][j] = f32x4{0.f, 0.f, 0.f, 0.f};

  const int wm = (w & 3) * 32;
  const int wn = (w >> 2) * 32;
  const int fr = lane & 15;
  const int kq = (lane >> 4) * 8;

  for (int k0 = 0; k0 < 256; k0 += 64) {
    const int r = t >> 2, c4 = (t & 3) * 16;
    float4 a4[4];
#pragma unroll
    for (int i = 0; i < 4; ++i)
      a4[i] = *(const float4*)(Ab + (size_t)r * 256 + k0 + c4 + 4 * i);
    const int kr = t >> 3, nc = (t & 7) * 8;
    float4 b4[2];
#pragma unroll
    for (int i = 0; i < 2; ++i)
      b4[i] = *(const float4*)(Bb + (size_t)(k0 + kr) * 4096 + n0 + nc + 4 * i);
    __syncthreads();
#pragma unroll
    for (int i = 0; i < 4; ++i) {
      bf16x4 v = {(bf16_t)a4[i].x, (bf16_t)a4[i].y, (bf16_t)a4[i].z, (bf16_t)a4[i].w};
      *(bf16x4*)&As[r][c4 + 4 * i] = v;
    }
#pragma unroll
    for (int i = 0; i < 2; ++i) {
      Bs[nc + 4 * i + 0][kr] = (bf16_t)b4[i].x;
      Bs[nc + 4 * i + 1][kr] = (bf16_t)b4[i].y;
      Bs[nc + 4 * i + 2][kr] = (bf16_t)b4[i].z;
      Bs[nc + 4 * i + 3][kr] = (bf16_t)b4[i].w;
    }
    __syncthreads();
#pragma unroll
    for (int kk = 0; kk < 64; kk += 32) {
      bf16x8 af[2], bg[2];
#pragma unroll
      for (int i = 0; i < 2; ++i) {
        af[i] = *(const bf16x8*)&As[wm + 16 * i + fr][kk + kq];
        bg[i] = *(const bf16x8*)&Bs[wn + 16 * i + fr][kk + kq];
      }
#pragma unroll
      for (int i = 0; i < 2; ++i)
#pragma unroll
        for (int j = 0; j < 2; ++j)
          acc[i][j] = __builtin_amdgcn_mfma_f32_16x16x32_bf16(af[i], bg[j], acc[i][j], 0, 0, 0);
    }
    __syncthreads();
  }

  bf16_t* Cb = C + (size_t)b * 524288;
  const int rh = (lane >> 4) * 4, col = lane & 15;
#pragma unroll
  for (int i = 0; i < 2; ++i)
#pragma unroll
    for (int j = 0; j < 2; ++j)
#pragma unroll
      for (int rr = 0; rr < 4; ++rr)
        Cb[(size_t)(wm + 16 * i + rh + rr) * 4096 + n0 + wn + 16 * j + col] =
            (bf16_t)acc[i][j][rr];
}

// ---------------- fused partF reduce + bias + silu -> fusb, then LN -> lnf ---
__global__ __launch_bounds__(256) void red_ln(
    const bf16_t* __restrict__ partF, int S,
    const float* __restrict__ bias,
    const float* __restrict__ g, const float* __restrict__ bta,
    bf16_t* __restrict__ fusb, bf16_t* __restrict__ lnf) {
  __shared__ float tmp[4];
  const int row = blockIdx.x;
  const int t = threadIdx.x;
  const long i0 = t * 16;
  float a[16];
#pragma unroll
  for (int j = 0; j < 16; ++j) a[j] = 0.f;
  for (int s = 0; s < S; ++s) {
    const bf16_t* p = partF + (size_t)s * 1048576 + (size_t)row * 4096 + i0;
    bf16x8 v0 = *(const bf16x8*)(p);
    bf16x8 v1 = *(const bf16x8*)(p + 8);
#pragma unroll
    for (int j = 0; j < 8; ++j) { a[j] += (float)v0[j]; a[8 + j] += (float)v1[j]; }
  }
#pragma unroll
  for (int j = 0; j < 16; ++j) a[j] = silu_f(a[j] + bias[i0 + j]);
  {
    bf16x8 o0, o1;
#pragma unroll
    for (int j = 0; j < 8; ++j) { o0[j] = (bf16_t)a[j]; o1[j] = (bf16_t)a[8 + j]; }
    *(bf16x8*)(fusb + (size_t)row * 4096 + i0) = o0;
    *(bf16x8*)(fusb + (size_t)row * 4096 + i0 + 8) = o1;
  }
  float s1 = 0.f, s2 = 0.f;
#pragma unroll
  for (int j = 0; j < 16; ++j) { s1 += a[j]; s2 += a[j] * a[j]; }
  s1 = block_sum(s1, tmp);
  s2 = block_sum(s2, tmp);
  const float mu = s1 / 4096.f;
  const float inv = rsqrtf(s2 / 4096.f - mu * mu + EPS);
  bf16x8 o0, o1;
#pragma unroll
  for (int j = 0; j < 8; ++j) {
    o0[j] = (bf16_t)((a[j] - mu) * inv * g[i0 + j] + bta[i0 + j]);
    o1[j] = (bf16_t)((a[8 + j] - mu) * inv * g[i0 + 8 + j] + bta[i0 + 8 + j]);
  }
  *(bf16x8*)(lnf + (size_t)row * 4096 + i0) = o0;
  *(bf16x8*)(lnf + (size_t)row * 4096 + i0 + 8) = o1;
}

// ---------------- fused partQ-reduce + LayerNorm(concat(refv, qb)) -> bf16 ---
__global__ __launch_bounds__(256) void ln_fuse(
    const float* __restrict__ refv, const bf16_t* __restrict__ partQ, int S,
    const float* __restrict__ g, const float* __restrict__ bta, bf16_t* __restrict__ Y) {
  __shared__ float tmp[4];
  const int row = blockIdx.x;
  const int t = threadIdx.x;
  const long i0 = t * 16;
  float q[16];
#pragma unroll
  for (int j = 0; j < 16; ++j) q[j] = 0.f;
  for (int s = 0; s < S; ++s) {
    const bf16_t* p = partQ + (size_t)s * 1048576 + (size_t)row * 4096 + i0;
    bf16x8 v0 = *(const bf16x8*)(p);
    bf16x8 v1 = *(const bf16x8*)(p + 8);
#pragma unroll
    for (int j = 0; j < 8; ++j) { q[j] += (float)v0[j]; q[8 + j] += (float)v1[j]; }
  }
  const float* xr = refv + (size_t)row * 4096 + i0;
  float r[16];
#pragma unroll
  for (int j = 0; j < 4; ++j) {
    float4 v = *(const float4*)(xr + 4 * j);
    r[4 * j] = v.x; r[4 * j + 1] = v.y; r[4 * j + 2] = v.z; r[4 * j + 3] = v.w;
  }
  float s1 = 0.f, s2 = 0.f;
#pragma unroll
  for (int j = 0; j < 16; ++j) { s1 += r[j] + q[j]; s2 += r[j] * r[j] + q[j] * q[j]; }
  s1 = block_sum(s1, tmp);
  s2 = block_sum(s2, tmp);
  const float mu = s1 / 8192.f;
  const float inv = rsqrtf(s2 / 8192.f - mu * mu + EPS);
  bf16_t* y = Y + (size_t)row * 8192;
  bf16x8 o0, o1;
#pragma unroll
  for (int j = 0; j < 8; ++j) {
    o0[j] = (bf16_t)((r[j] - mu) * inv * g[i0 + j] + bta[i0 + j]);
    o1[j] = (bf16_t)((r[8 + j] - mu) * inv * g[i0 + 8 + j] + bta[i0 + 8 + j]);
  }
  *(bf16x8*)(y + i0) = o0;
  *(bf16x8*)(y + i0 + 8) = o1;
#pragma unroll
  for (int j = 0; j < 8; ++j) {
    o0[j] = (bf16_t)((q[j] - mu) * inv * g[4096 + i0 + j] + bta[4096 + i0 + j]);
    o1[j] = (bf16_t)((q[8 + j] - mu) * inv * g[4096 + i0 + 8 + j] + bta[4096 + i0 + 8 + j]);
  }
  *(bf16x8*)(y + 4096 + i0) = o0;
  *(bf16x8*)(y + 4096 + i0 + 8) = o1;
}

// ---------------- fused part8-reduce + QW ----------------
__global__ __launch_bounds__(256) void qw_fuse(
    const float* __restrict__ part8, const float* __restrict__ kW, float* __restrict__ QW) {
  __shared__ float q[256];
  const int bk = blockIdx.x;
  const int c = threadIdx.x;
  float sq = 0.f;
#pragma unroll
  for (int s = 0; s < 8; ++s) sq += part8[(size_t)s * 65536 + (size_t)bk * 256 + c];
  q[c] = 0.125f * sq;
  __syncthreads();
#pragma unroll
  for (int h = 0; h < 4; ++h) {
    float s = 0.f;
#pragma unroll 8
    for (int d = 0; d < 64; ++d)
      s += q[(h << 6) + d] * kW[(size_t)(((h << 6) + d) << 8) + c];
    QW[((size_t)(bk * 4 + h) << 8) + c] = s;
  }
}

// ---------------- fused conv1(4->4,silu) + conv2(4->1) + bilinear up ----------
__global__ __launch_bounds__(256) void conv_fused(
    const bf16_t* __restrict__ X, const float* __restrict__ W1,
    const float* __restrict__ B1, const float* __restrict__ W2,
    const float* __restrict__ B2, float* __restrict__ O) {
  __shared__ bf16_t lg[16384];
  __shared__ bf16_t mid[16384];
  __shared__ float lg64[4096];
  __shared__ float wsh[180];
  const int t = threadIdx.x;
  const size_t base = (size_t)blockIdx.x * 16384;
#pragma unroll
  for (int i = 0; i < 8; ++i) {
    int o = (i * 256 + t) * 8;
    *(bf16x8*)&lg[o] = *(const bf16x8*)(X + base + o);
  }
  if (t < 144) wsh[t] = W1[t];
  else if (t < 180) wsh[t] = W2[t - 144];
  __syncthreads();
  const int px0 = (t & 15) * 4, py0 = (t >> 4) * 4;
  {
    float acc1[4][16];
#pragma unroll
    for (int oc = 0; oc < 4; ++oc) {
      float bb = B1[oc];
#pragma unroll
      for (int p = 0; p < 16; ++p) acc1[oc][p] = bb;
    }
#pragma unroll
    for (int c = 0; c < 4; ++c) {
      float p[6][6];
#pragma unroll
      for (int yy = 0; yy < 6; ++yy) {
        int gy = py0 + yy - 1;
#pragma unroll
        for (int xx = 0; xx < 6; ++xx) {
          int gx = px0 + xx - 1;
          p[yy][xx] = ((unsigned)gy < 64u && (unsigned)gx < 64u)
                          ? (float)lg[c * 4096 + gy * 64 + gx] : 0.f;
        }
      }
#pragma unroll
      for (int oc = 0; oc < 4; ++oc) {
        float wr[9];
#pragma unroll
        for (int k = 0; k < 9; ++k) wr[k] = wsh[oc * 36 + c * 9 + k];
#pragma unroll
        for (int y = 0; y < 4; ++y)
#pragma unroll
          for (int x = 0; x < 4; ++x)
            acc1[oc][y * 4 + x] +=
                wr[0] * p[y][x] + wr[1] * p[y][x + 1] + wr[2] * p[y][x + 2]
              + wr[3] * p[y + 1][x] + wr[4] * p[y + 1][x + 1] + wr[5] * p[y + 1][x + 2]
              + wr[6] * p[y + 2][x] + wr[7] * p[y + 2][x + 1] + wr[8] * p[y + 2][x + 2];
      }
    }
#pragma unroll
    for (int oc = 0; oc < 4; ++oc)
#pragma unroll
      for (int y = 0; y < 4; ++y) {
        bf16x4 o;
#pragma unroll
        for (int x = 0; x < 4; ++x) o[x] = (bf16_t)silu_f(acc1[oc][y * 4 + x]);
        *(bf16x4*)&mid[oc * 4096 + (py0 + y) * 64 + px0] = o;
      }
  }
  __syncthreads();
  {
    float acc2[16];
    float bb = B2[0];
#pragma unroll
    for (int p = 0; p < 16; ++p) acc2[p] = bb;
#pragma unroll
    for (int c = 0; c < 4; ++c) {
      float p[6][6];
#pragma unroll
      for (int yy = 0; yy < 6; ++yy) {
        int gy = py0 + yy - 1;
#pragma unroll
        for (int xx = 0; xx < 6; ++xx) {
          int gx = px0 + xx - 1;
          p[yy][xx] = ((unsigned)gy < 64u && (unsigned)gx < 64u)
                          ? (float)mid[c * 4096 + gy * 64 + gx] : 0.f;
        }
      }
      float wr[9];
#pragma unroll
      for (int k = 0; k < 9; ++k) wr[k] = wsh[144 + c * 9 + k];
#pragma unroll
      for (int y = 0; y < 4; ++y)
#pragma unroll
        for (int x = 0; x < 4; ++x)
          acc2[y * 4 + x] +=
              wr[0] * p[y][x] + wr[1] * p[y][x + 1] + wr[2] * p[y][x + 2]
            + wr[3] * p[y + 1][x] + wr[4] * p[y + 1][x + 1] + wr[5] * p[y + 1][x + 2]
            + wr[6] * p[y + 2][x] + wr[7] * p[y + 2][x + 1] + wr[8] * p[y + 2][x + 2];
    }
#pragma unroll
    for (int y = 0; y < 4; ++y)
#pragma unroll
      for (int x = 0; x < 4; ++x) lg64[(py0 + y) * 64 + px0 + x] = acc2[y * 4 + x];
  }
  __syncthreads();
  float* Ob = O + (size_t)blockIdx.x * 65536;
  for (int rr = 0; rr < 64; ++rr) {
    int p4 = rr * 256 + t;
    int oy = p4 >> 6, ox0 = (p4 & 63) * 4;
    float sy = oy * 0.25f - 0.375f;
    int y0 = (int)floorf(sy);
    float wy = sy - (float)y0;
    int y1 = min(y0 + 1, 63); y0 = max(y0, 0);
    const float* r0 = &lg64[y0 * 64];
    const float* r1 = &lg64[y1 * 64];
    float4 o;
#pragma unroll
    for (int q = 0; q < 4; ++q) {
      int ox = ox0 + q;
      float sx = ox * 0.25f - 0.375f;
      int x0 = (int)floorf(sx);
      float wx = sx - (float)x0;
      int x1 = min(x0 + 1, 63); x0 = max(x0, 0);
      float v0 = r0[x0] + wx * (r0[x1] - r0[x0]);
      float v1 = r1[x0] + wx * (r1[x1] - r1[x0]);
      ((float*)&o)[q] = v0 + wy * (v1 - v0);
    }
    *(float4*)(Ob + oy * 256 + ox0) = o;
  }
}

// ---------------- fused partC reduce + bias + silu + dot(w2) + b2 ------------
__global__ __launch_bounds__(256) void conf_fuse(
    const bf16_t* __restrict__ partC, int S,
    const float* __restrict__ cb1, const float* __restrict__ w2,
    const float* __restrict__ b2, float* __restrict__ out) {
  __shared__ float tmp[4];
  const int row = blockIdx.x;
  const int t = threadIdx.x;
  const long i0 = t * 8;
  float a[8];
#pragma unroll
  for (int j = 0; j < 8; ++j) a[j] = 0.f;
  for (int s = 0; s < S; ++s) {
    bf16x8 v = *(const bf16x8*)(partC + (size_t)s * 524288 + (size_t)row * 2048 + i0);
#pragma unroll
    for (int j = 0; j < 8; ++j) a[j] += (float)v[j];
  }
  float dot = 0.f;
#pragma unroll
  for (int j = 0; j < 8; ++j) dot += silu_f(a[j] + cb1[i0 + j]) * w2[i0 + j];
  dot = block_sum(dot, tmp);
  if (t == 0) out[row] = dot + b2[0];
}

extern "C" void kernel_launch(void* const* d_in, const int* in_sizes, int n_in,
                              void* d_out, int out_size, void* d_ws, size_t ws_size,
                              hipStream_t stream) {
  const float* img    = (const float*)d_in[0];
  const float* refv   = (const float*)d_in[1];
  const float* qs     = (const float*)d_in[2];
  const float* qpw    = (const float*)d_in[3];
  const float* kpw    = (const float*)d_in[4];
  const float* fw1    = (const float*)d_in[5];
  const float* fb1    = (const float*)d_in[6];
  const float* fw2    = (const float*)d_in[7];
  const float* fb2    = (const float*)d_in[8];
  const float* qbw    = (const float*)d_in[9];
  const float* rlg    = (const float*)d_in[10];
  const float* rlb    = (const float*)d_in[11];
  const float* rlw    = (const float*)d_in[12];
  const float* rlbias = (const float*)d_in[13];
  const float* clg    = (const float*)d_in[14];
  const float* clb    = (const float*)d_in[15];
  const float* cw1    = (const float*)d_in[16];
  const float* cb1    = (const float*)d_in[17];
  const float* cw2    = (const float*)d_in[18];
  const float* cb2    = (const float*)d_in[19];
  float* out = (float*)d_out;
  char* W = (char*)d_ws;

  // --- workspace layout (bytes); disjoint lifetimes per region ---
  bf16_t* partQ = (bf16_t*)(W + 0);          // 16.8 MB steps 1-2
  bf16_t* partF = (bf16_t*)(W + 0);          // 16.8 MB steps 3-4 (partQ dead)
  bf16_t* l64hb = (bf16_t*)(W + 0);          //  8.4 MB steps 7-8 (partF dead)
  bf16_t* partC = (bf16_t*)(W + 0);          // 16.8 MB steps 9-10 (l64hb dead)
  bf16_t* catln = (bf16_t*)(W + 16777216);   //  4.2 MB steps 2-3 (dead by step 9)
  bf16_t* fusb  = (bf16_t*)(W + 20971520);   //  2.1 MB steps 4-5
  bf16_t* lnf   = (bf16_t*)(W + 23068672);   //  2.1 MB steps 4-9
  float*  part8 = (float*)(W + 25165824);    //  2.1 MB steps 5-6
  float*  QW    = (float*)(W + 27262976);    //  1.1 MB steps 6-7

  dim3 b256(256);

  // 1. qb GEMM (split-K x8): partQ[s] = qs @ qbw^T chunk
  gemm_wide_s<<<dim3(32, 8), dim3(1024), 0, stream>>>(qs, qbw, partQ, 4096, 512, 64);
  // 2. catln = LN(concat(refv, sum partQ)) -> bf16
  ln_fuse<<<dim3(256), b256, 0, stream>>>(refv, partQ, 8, rlg, rlb, catln);
  // 3. fused GEMM (split-K x8, global_load_lds): partF[s] = catln @ rlw^T chunk
  gemm_gll<<<dim3(32, 8), dim3(1024), 0, stream>>>(catln, rlw, partF, 4096, 8192, 1024);
  // 4. fusb = silu(sum partF + bias); lnf = LN(fusb)
  red_ln<<<dim3(256), b256, 0, stream>>>(partF, 8, rlbias, clg, clb, fusb, lnf);
  // 5. qproj GEMM (split-K x8): part8[s] = fusb @ qpw^T chunk
  gemm_small<<<dim3(4, 4, 8), b256, 0, stream>>>(fusb, qpw, part8, 256, 256, 4096, 512, 8);
  // 6. QW = per-head (0.125 * sum part8) @ k_proj
  qw_fuse<<<dim3(256), b256, 0, stream>>>(part8, kpw, QW);
  // 7. logits (full-M): l64hb[b] = QW_b @ img_b
  gemm_attn<<<dim3(64, 8), dim3(512), 0, stream>>>(QW, img, l64hb);
  // 8. out = upsample(conv2(silu(conv1(l64hb))))
  conv_fused<<<dim3(256), b256, 0, stream>>>(l64hb, fw1, fb1, fw2, fb2, out);
  // 9. cfh GEMM (split-K x16, FULL grid = 256 blocks): partC[s] = lnf @ cw1^T
  gemm_gll<<<dim3(16, 16), dim3(1024), 0, stream>>>(lnf, cw1, partC, 2048, 4096, 256);
  // 10. conf out = silu(sum partC + cb1) . w2 + b2
  conf_fuse<<<dim3(256), b256, 0, stream>>>(partC, 16, cb1, cw2, cb2, out + 16777216);
}